// Round 1
// baseline (1142.108 us; speedup 1.0000x reference)
//
#include <hip/hip_runtime.h>

#define NTHR 1024
#define KV 13            // ceil(12564 / 1024) float4 iters per thread
#define VN 50257
#define TOPK 500
#define NBUCK 8192
#define KSHIFT 19        // 32 - 13 bits
#define TIE_CAP 2048
#define SURV_CAP 1024
#define MARGIN 0.2f

__device__ __forceinline__ unsigned fkey(float x) {
    unsigned b = __float_as_uint(x);
    return (b & 0x80000000u) ? ~b : (b | 0x80000000u);
}

__global__ void zero_acc_k(double* acc) { *acc = 0.0; }
__global__ void finalize_k(const double* acc, float* out) { out[0] = (float)(*acc); }

__global__ __launch_bounds__(NTHR, 1) void adalab_k(
    const float* __restrict__ outp,
    const int* __restrict__ target,
    const float* __restrict__ ls,
    double* __restrict__ acc)
{
    const int row = blockIdx.x;
    const int t = threadIdx.x;
    const int tgt = target[row];
    if (tgt == 0) return;   // ignore_index rows contribute exactly 0

    __shared__ unsigned hist[NBUCK];
    __shared__ int sfx[NTHR];
    __shared__ float tval[TIE_CAP];
    __shared__ int tidx[TIE_CAP];
    __shared__ int sidx[SURV_CAP];
    __shared__ float sval[SURV_CAP];
    __shared__ float wr1[NTHR / 64], wr2[NTHR / 64];
    __shared__ float sh_m2, sh_Tup, sh_ot, sh_omax, sh_S, sh_W, sh_A;
    __shared__ int sh_tstar, sh_B, sh_Cgt, sh_ntie, sh_nsurv;

    #pragma unroll
    for (int i = 0; i < NBUCK / NTHR; ++i) hist[t + i * NTHR] = 0u;
    if (t == 0) {
        sh_S = 0.f; sh_W = 0.f; sh_A = 0.f;
        sh_ntie = 0; sh_nsurv = 0; sh_Tup = INFINITY; sh_tstar = 0; sh_ot = 0.f;
    }
    __syncthreads();

    const size_t base = (size_t)row * VN;
    const float* lsr = ls + base;
    const float* outr = outp + base;
    const int lead = (int)((4 - (base & 3)) & 3);   // align to float4 (V % 4 == 1)
    const int nv4 = (VN - lead) >> 2;
    const int tail0 = lead + (nv4 << 2);
    const int ntail = VN - tail0;

    // ---- single global pass over label row: keep in registers ----
    float vb[KV][4];
    const float4* lp = reinterpret_cast<const float4*>(lsr + lead);
    #pragma unroll
    for (int k = 0; k < KV; ++k) {
        int q = k * NTHR + t;
        if (q < nv4) {
            float4 v = lp[q];
            vb[k][0] = v.x; vb[k][1] = v.y; vb[k][2] = v.z; vb[k][3] = v.w;
        }
    }
    float xval = 0.f; int xj = -1;                  // head/tail scalars (<=6 per row)
    if (t < lead)                { xj = t;                 xval = lsr[xj]; }
    else if (t - lead < ntail)   { xj = tail0 + (t - lead); xval = lsr[xj]; }

    // ---- histogram + top-2 ----
    float m1 = -INFINITY, m2l = -INFINITY;
    #pragma unroll
    for (int k = 0; k < KV; ++k) {
        int q = k * NTHR + t;
        if (q < nv4) {
            int j0 = lead + (q << 2);
            #pragma unroll
            for (int m = 0; m < 4; ++m) {
                int j = j0 + m;
                if (j != 0 && j != tgt) {
                    float x = vb[k][m];
                    atomicAdd(&hist[fkey(x) >> KSHIFT], 1u);
                    m2l = fmaxf(m2l, fminf(m1, x));
                    m1 = fmaxf(m1, x);
                }
            }
        }
    }
    if (xj > 0 && xj != tgt) {
        atomicAdd(&hist[fkey(xval) >> KSHIFT], 1u);
        m2l = fmaxf(m2l, fminf(m1, xval));
        m1 = fmaxf(m1, xval);
    }

    const int lane = t & 63, wid = t >> 6;
    #pragma unroll
    for (int off = 32; off; off >>= 1) {
        float o1 = __shfl_down(m1, off);
        float o2 = __shfl_down(m2l, off);
        m2l = fmaxf(m2l, fmaxf(o2, fminf(m1, o1)));
        m1 = fmaxf(m1, o1);
    }
    if (lane == 0) { wr1[wid] = m1; wr2[wid] = m2l; }
    __syncthreads();
    if (t == 0) {
        float a1 = wr1[0], a2 = wr2[0];
        for (int i = 1; i < NTHR / 64; ++i) {
            float b1 = wr1[i], b2 = wr2[i];
            a2 = fmaxf(a2, fmaxf(b2, fminf(a1, b1)));
            a1 = fmaxf(a1, b1);
        }
        sh_m2 = a2;               // kth_lower: 2nd largest (with multiplicity)
    }
    __syncthreads();
    const float M2 = sh_m2;

    // ---- suffix scan over histogram to find rank-500 bucket ----
    int ps = 0;
    #pragma unroll
    for (int i = 0; i < 8; ++i) ps += (int)hist[(t << 3) + i];
    sfx[t] = ps;
    __syncthreads();
    for (int off = 1; off < NTHR; off <<= 1) {
        int v = sfx[t] + ((t + off < NTHR) ? sfx[t + off] : 0);
        __syncthreads();
        sfx[t] = v;
        __syncthreads();
    }
    if (sfx[t] >= TOPK && (t == NTHR - 1 || sfx[t + 1] < TOPK)) sh_tstar = t;
    __syncthreads();
    if (t == 0) {
        int g = sh_tstar;
        int cum = (g == NTHR - 1) ? 0 : sfx[g + 1];
        int Bb = g << 3, cgt = cum;
        for (int b = (g << 3) + 7; b >= (g << 3); --b) {
            int h = (int)hist[b];
            if (cum + h >= TOPK) { Bb = b; cgt = cum; break; }
            cum += h;
        }
        sh_B = Bb; sh_Cgt = cgt;
    }
    __syncthreads();
    const unsigned Bb = (unsigned)sh_B;

    // ---- rescan registers: classify above-bucket / tie-bucket ----
    float S_l = 0.f, W_l = 0.f;
    #pragma unroll
    for (int k = 0; k < KV; ++k) {
        int q = k * NTHR + t;
        if (q < nv4) {
            int j0 = lead + (q << 2);
            #pragma unroll
            for (int m = 0; m < 4; ++m) {
                int j = j0 + m;
                if (j != 0 && j != tgt) {
                    float x = vb[k][m];
                    unsigned bk = fkey(x) >> KSHIFT;
                    if (bk > Bb) {
                        if (x <= M2) {   // drop the strict max (kth_lower rule)
                            float e = expf(x - M2);
                            S_l += e; W_l += e * (x - M2);
                            int p = atomicAdd(&sh_nsurv, 1);
                            if (p < SURV_CAP) { sidx[p] = j; sval[p] = e; }
                        }
                    } else if (bk == Bb) {
                        int p = atomicAdd(&sh_ntie, 1);
                        if (p < TIE_CAP) { tval[p] = x; tidx[p] = j; }
                    }
                }
            }
        }
    }
    if (xj > 0 && xj != tgt) {
        unsigned bk = fkey(xval) >> KSHIFT;
        if (bk > Bb) {
            if (xval <= M2) {
                float e = expf(xval - M2);
                S_l += e; W_l += e * (xval - M2);
                int p = atomicAdd(&sh_nsurv, 1);
                if (p < SURV_CAP) { sidx[p] = xj; sval[p] = e; }
            }
        } else if (bk == Bb) {
            int p = atomicAdd(&sh_ntie, 1);
            if (p < TIE_CAP) { tval[p] = xval; tidx[p] = xj; }
        }
    }
    __syncthreads();

    // ---- exact rank select inside tie bucket (tie-correct like top_k) ----
    const int r = TOPK - sh_Cgt;
    const int ntie = min(sh_ntie, TIE_CAP);
    for (int i = t; i < ntie; i += NTHR) {
        float x = tval[i];
        int cgt = 0, ceq = 0;
        for (int p = 0; p < ntie; ++p) {
            float v2 = tval[p];
            cgt += (v2 > x); ceq += (v2 == x);
        }
        if (cgt < r && cgt + ceq >= r) sh_Tup = x;
    }
    __syncthreads();
    const float Tup = sh_Tup;
    for (int i = t; i < ntie; i += NTHR) {
        float x = tval[i];
        if (x >= Tup && x <= M2) {
            float e = expf(x - M2);
            S_l += e; W_l += e * (x - M2);
            int p = atomicAdd(&sh_nsurv, 1);
            if (p < SURV_CAP) { sidx[p] = tidx[i]; sval[p] = e; }
        }
    }
    #pragma unroll
    for (int off = 32; off; off >>= 1) {
        S_l += __shfl_down(S_l, off);
        W_l += __shfl_down(W_l, off);
    }
    if (lane == 0) { atomicAdd(&sh_S, S_l); atomicAdd(&sh_W, W_l); }

    // ---- single global pass over output row: max + target grab ----
    float omax_l = -INFINITY;
    const float4* op4 = reinterpret_cast<const float4*>(outr + lead);
    #pragma unroll
    for (int k = 0; k < KV; ++k) {
        int q = k * NTHR + t;
        if (q < nv4) {
            float4 o = op4[q];
            int j0 = lead + (q << 2);
            omax_l = fmaxf(fmaxf(fmaxf(o.x, o.y), fmaxf(o.z, o.w)), omax_l);
            if (tgt >= j0 && tgt < j0 + 4) {
                sh_ot = (tgt == j0) ? o.x : (tgt == j0 + 1) ? o.y
                      : (tgt == j0 + 2) ? o.z : o.w;
            }
        }
    }
    if (xj >= 0) {
        float o = outr[xj];
        omax_l = fmaxf(omax_l, o);
        if (xj == tgt) sh_ot = o;
    }
    #pragma unroll
    for (int off = 32; off; off >>= 1)
        omax_l = fmaxf(omax_l, __shfl_down(omax_l, off));
    if (lane == 0) wr1[wid] = omax_l;
    __syncthreads();
    if (t == 0) {
        float a = wr1[0];
        for (int i = 1; i < NTHR / 64; ++i) a = fmaxf(a, wr1[i]);
        sh_omax = a;
    }
    __syncthreads();

    // ---- gather survivor outputs: A = sum e_j * o_j (L2-hot) ----
    const int nsurv = min(sh_nsurv, SURV_CAP);
    float A_l = 0.f;
    for (int i = t; i < nsurv; i += NTHR) A_l += sval[i] * outr[sidx[i]];
    #pragma unroll
    for (int off = 32; off; off >>= 1) A_l += __shfl_down(A_l, off);
    if (lane == 0) atomicAdd(&sh_A, A_l);
    __syncthreads();

    if (t == 0) {
        float S = sh_S, W = sh_W;
        float A = sh_A / S;                 // sum v_j * o_j
        float vmax = 1.0f / S;              // max of softmax(v)
        float ub = 1.0f / (1.0f + vmax) - MARGIN;
        float pmax = expf(sh_omax);
        float pg = expf(sh_ot);
        float eps0 = 1.0f - pmax;
        float eps = (eps0 > ub) ? ub : eps0;
        float ratio = pg / pmax;
        eps *= ratio * ratio;
        float conf = 1.0f - eps;
        float loss = conf * (logf(conf) - sh_ot);
        if (eps > 0.0f)
            loss += eps * logf(eps) + eps * (W / S - logf(S)) - eps * A;
        atomicAdd(acc, (double)loss);
    }
}

extern "C" void kernel_launch(void* const* d_in, const int* in_sizes, int n_in,
                              void* d_out, int out_size, void* d_ws, size_t ws_size,
                              hipStream_t stream) {
    const float* outp = (const float*)d_in[0];
    const int* tgt    = (const int*)d_in[1];
    const float* ls   = (const float*)d_in[2];
    float* out        = (float*)d_out;
    double* acc       = (double*)d_ws;
    const int Bn = in_sizes[1];

    hipLaunchKernelGGL(zero_acc_k, dim3(1), dim3(1), 0, stream, acc);
    hipLaunchKernelGGL(adalab_k, dim3(Bn), dim3(NTHR), 0, stream, outp, tgt, ls, acc);
    hipLaunchKernelGGL(finalize_k, dim3(1), dim3(1), 0, stream, acc, out);
}